// Round 13
// baseline (169.132 us; speedup 1.0000x reference)
//
#include <hip/hip_runtime.h>

typedef float f4  __attribute__((ext_vector_type(4)));
typedef short s8v __attribute__((ext_vector_type(8)));
typedef short s4v __attribute__((ext_vector_type(4)));

#define BB    2
#define DDIM  1024
#define LSEQ  8192
#define LC    128
#define TD    4       // channels per block = 1 group = 1 wave (64-thread blocks)
#define TL    512     // l-extent per block
#define HALO  128
#define ZSTR  648     // bf16 row stride: 640 data + 8 pad

// round-to-nearest-even fp32 -> bf16, packed pair (lo in bits 0-15)
__device__ __forceinline__ unsigned bf16pk(float lo, float hi) {
    unsigned a = __float_as_uint(lo), b = __float_as_uint(hi);
    a = (a + 0x7FFFu + ((a >> 16) & 1u)) >> 16;
    b = (b + 0x7FFFu + ((b >> 16) & 1u));
    return (a & 0xFFFFu) | (b & 0xFFFF0000u);
}
__device__ __forceinline__ float bf2f(short s) {
    return __uint_as_float(((unsigned)(unsigned short)s) << 16);
}

union U8 { s8v s; unsigned u[4]; };

// Single-wave workgroup: barriers are wave-local (no convoy), blocks fully
// independent. VGPR cap stays 128 (2nd arg 4): R6/R7 proved tighter caps spill.
__global__ __launch_bounds__(64, 4) void hyena_mfma_kernel(
    const float* __restrict__ x1,
    const float* __restrict__ x2,
    const float* __restrict__ v,
    const float* __restrict__ h,
    const float* __restrict__ cb,
    float* __restrict__ out)
{
    __shared__ union SM {
        short zb[TD][ZSTR];   // z (bf16) tile + halo (5184 B)
        f4 ob[TD][64];        // fp32 out staging, half tile (4 KB)
    } sm;

    const int t = threadIdx.x;    // lane 0..63

    // ---- XCD decode: all 256 g-blocks of one (b,l0) share an XCD (and are
    //      co-resident) so the XCD L2 assembles full 4KB output lines ----
    const int flat = blockIdx.x;           // [0, 8192)
    const int xcd  = flat & 7;
    const int rr_  = flat >> 3;            // [0,1024)
    const int g    = rr_ & 255;
    const int c_   = xcd + 8*(rr_ >> 8);   // [0,32)
    const int l0   = (c_ & 15) * TL;
    const int b    = c_ >> 4;
    const int d0   = g * 4;

    // ---- phase 0: issue ALL z-staging loads into registers ----
    const int r = t >> 4, sidx = t & 15;   // 4 rows x 16 lane-columns
    const size_t rb = ((size_t)(b*DDIM + d0 + r)) * LSEQ;
    f4 xa0[5], xa1[5], xw0[5], xw1[5];
    #pragma unroll
    for (int it = 0; it < 5; ++it) {
        const int gl = l0 - HALO + (sidx + 16*it)*8;
        if (gl >= 0) {
            xa0[it] = *(const f4*)(x2 + rb + gl);
            xa1[it] = *(const f4*)(x2 + rb + gl + 4);
            xw0[it] = *(const f4*)(v  + rb + gl);
            xw1[it] = *(const f4*)(v  + rb + gl + 4);
        }
    }

    // ---- convert staged regs -> bf16 z in LDS ----
    #pragma unroll
    for (int it = 0; it < 5; ++it) {
        const int s = sidx + 16*it;
        const int gl = l0 - HALO + s*8;
        U8 zz; zz.s = (s8v){0,0,0,0,0,0,0,0};
        if (gl >= 0) {
            const f4 z0 = xa0[it]*xw0[it], z1 = xa1[it]*xw1[it];
            zz.u[0] = bf16pk(z0[0], z0[1]);
            zz.u[1] = bf16pk(z0[2], z0[3]);
            zz.u[2] = bf16pk(z1[0], z1[1]);
            zz.u[3] = bf16pk(z1[2], z1[3]);
        }
        *(s8v*)&sm.zb[r][s*8] = zz.s;
    }

    // ---- lane geometry (MFMA 16x16x32) + x1 prefetch ----
    const int j  = t & 15, kb = t >> 4;
    const int qj = j & 3,  cc = j >> 2;
    const int row = cc;                    // channel within block
    const size_t chb = ((size_t)(b*DDIM + d0 + row)) * LSEQ + l0;
    f4 x1r[8];
    #pragma unroll
    for (int ci = 0; ci < 8; ++ci)
        x1r[ci] = *(const f4*)(x1 + chb + 64*ci + 16*qj + 4*kb);
    const float bd = cb[d0 + row];

    // ---- A-frags IN REGISTERS: A_u[i,p] = k[i - p + 16 + 32u],
    //      k[m] = h[g,m]*exp(-dd*m/127); exp via recurrence ----
    const float* __restrict__ hg = h + g*LC;
    const float dd = __expf((float)g * (2.0f/255.0f) * 2.302585092994046f); // 10^(2g/255)
    const float t0 = dd * (1.0f/127.0f);
    const int   M0base = j - 8*kb + 16;
    const float rE = __expf(t0);
    const float sU = __expf(-32.0f*t0);
    float pE[8];
    pE[0] = 1.0f;
    #pragma unroll
    for (int e = 1; e < 8; ++e) pE[e] = pE[e-1]*rE;
    float baseU = __expf(-t0*(float)M0base);

    s8v afr[5];
    #pragma unroll
    for (int u = 0; u < 5; ++u) {
        const int M0 = M0base + 32*u;
        float kv[8];
        #pragma unroll
        for (int e = 0; e < 8; ++e) {
            const int m = M0 - e;
            const int mc = m < 0 ? 0 : (m > 127 ? 127 : m);
            const float hv = hg[mc];
            const float w  = ((unsigned)m < 128u) ? baseU*pE[e] : 0.0f;
            kv[e] = hv * w;
        }
        U8 aa;
        aa.u[0] = bf16pk(kv[0], kv[1]);
        aa.u[1] = bf16pk(kv[2], kv[3]);
        aa.u[2] = bf16pk(kv[4], kv[5]);
        aa.u[3] = bf16pk(kv[6], kv[7]);
        afr[u] = aa.s;
        baseU *= sU;
    }
    __syncthreads();   // single-wave: just orders LDS writes before reads

    // ---- 8 chains: 5 banded-Toeplitz MFMAs each; bias from LDS z; gate x1 ----
    f4 ov[8];
    #pragma unroll
    for (int ci = 0; ci < 8; ++ci) {
        const int L = 64*ci + 16*qj;
        f4 acc = {0.f, 0.f, 0.f, 0.f};
        #pragma unroll
        for (int u = 0; u < 5; ++u) {
            int bi = 112 + L + 8*kb - 32*u;    // zb idx incl. halo
            bi = bi < 0 ? 0 : bi;              // clamped reads pair with A == 0
            const s8v bf = *(const s8v*)&sm.zb[row][bi];
            acc = __builtin_amdgcn_mfma_f32_16x16x32_bf16(afr[u], bf, acc, 0, 0, 0);
        }
        const int lo = L + 4*kb;
        const s4v z4 = *(const s4v*)&sm.zb[row][HALO + lo];
        f4 o;
        o[0] = (acc[0] + bf2f(z4[0])*bd) * x1r[ci][0];
        o[1] = (acc[1] + bf2f(z4[1])*bd) * x1r[ci][1];
        o[2] = (acc[2] + bf2f(z4[2])*bd) * x1r[ci][2];
        o[3] = (acc[3] + bf2f(z4[3])*bd) * x1r[ci][3];
        ov[ci] = o;
    }

    // ---- output transpose in two half-phases via 4 KB ob (aliases dead zb) ----
    #pragma unroll
    for (int hp = 0; hp < 2; ++hp) {
        __syncthreads();                       // zb dead / prev half drained
        #pragma unroll
        for (int ci = 0; ci < 4; ++ci) {
            const int cidx = hp*4 + ci;
            const int J = (4*cidx + qj)*4 + kb - hp*64;   // [0,64)
            sm.ob[row][J] = ov[cidx];          // banks balanced at TD=4, no XOR
        }
        __syncthreads();
        #pragma unroll
        for (int it = 0; it < 4; ++it) {
            const int ll = t + it*64;          // local l in [0,256)
            const int J = ll >> 2, e = ll & 3;
            f4 o;
            #pragma unroll
            for (int c2 = 0; c2 < 4; ++c2)
                o[c2] = ((const float*)&sm.ob[c2][J])[e];
            __builtin_nontemporal_store(o,
                (f4*)(out + ((size_t)b*LSEQ + l0 + hp*256 + ll)*DDIM + d0));
        }
    }
}

extern "C" void kernel_launch(void* const* d_in, const int* in_sizes, int n_in,
                              void* d_out, int out_size, void* d_ws, size_t ws_size,
                              hipStream_t stream) {
    const float* x1 = (const float*)d_in[0];
    const float* x2 = (const float*)d_in[1];
    const float* v  = (const float*)d_in[2];
    const float* h  = (const float*)d_in[3];
    const float* cb = (const float*)d_in[4];
    float* outp = (float*)d_out;
    hipLaunchKernelGGL(hyena_mfma_kernel, dim3(8192), dim3(64), 0, stream,
                       x1, x2, v, h, cb, outp);
}

// Round 14
// 48.878 us; speedup vs baseline: 3.4603x; 3.4603x over previous
//
#include <hip/hip_runtime.h>

typedef float f4  __attribute__((ext_vector_type(4)));
typedef short s8v __attribute__((ext_vector_type(8)));
typedef short s4v __attribute__((ext_vector_type(4)));

#define BB    2
#define DDIM  1024
#define LSEQ  8192
#define LC    128
#define TD    16      // channels per block = 4 groups, 1 group per wave
#define TL    1024    // l-extent per block: two 512-l subtiles share one staging
#define HALO  128
#define ZSTR  1160    // bf16 row stride: 1152 data + 8 pad
#define OB2   64      // f4 per row: 256-l transpose staging (16 KB)

// round-to-nearest-even fp32 -> bf16, packed pair (lo in bits 0-15)
__device__ __forceinline__ unsigned bf16pk(float lo, float hi) {
    unsigned a = __float_as_uint(lo), b = __float_as_uint(hi);
    a = (a + 0x7FFFu + ((a >> 16) & 1u)) >> 16;
    b = (b + 0x7FFFu + ((b >> 16) & 1u));
    return (a & 0xFFFFu) | (b & 0xFFFF0000u);
}
__device__ __forceinline__ float bf2f(short s) {
    return __uint_as_float(((unsigned)(unsigned short)s) << 16);
}

union U8 { s8v s; unsigned u[4]; };

// VGPR: peak ~104 (20-f4 staging round / afr+x1r+ov in chains). bounds(256,3)
// caps ~170 — NO tighter (R6/R7: tight caps spilled staging to scratch).
__global__ __launch_bounds__(256, 3) void hyena_mfma_kernel(
    const float* __restrict__ x1,
    const float* __restrict__ x2,
    const float* __restrict__ v,
    const float* __restrict__ h,
    const float* __restrict__ cb,
    float* __restrict__ out)
{
    __shared__ short zb[TD][ZSTR];   // z (bf16) 1024-l tile + halo (36.25 KB)
    __shared__ f4    ob[TD][OB2];    // fp32 out staging, 256 l (16 KB)

    const int t = threadIdx.x;

    // ---- XCD decode: all 64 d0-blocks of one (l0,b) share an XCD ----
    const int flat = blockIdx.x;           // [0,1024)
    const int xcd  = flat & 7;
    const int rr_  = flat >> 3;            // [0,128)
    const int d0   = (rr_ & 63) * TD;
    const int c_   = xcd + 8*(rr_ >> 6);   // [0,16)
    const int l0   = (c_ & 7) * TL;
    const int b    = c_ >> 3;

    const int r = t & 15, sidx = t >> 4;   // 16 rows x 16 lane-columns
    const size_t rb = ((size_t)(b*DDIM + d0 + r)) * LSEQ;

    // ---- staging round A: slots 0..79 (20 f4 in flight), convert, ds_write ----
    {
        f4 xa0[5], xa1[5], xw0[5], xw1[5];
        #pragma unroll
        for (int it = 0; it < 5; ++it) {
            const int gl = l0 - HALO + (sidx + 16*it)*8;
            if (gl >= 0) {
                xa0[it] = *(const f4*)(x2 + rb + gl);
                xa1[it] = *(const f4*)(x2 + rb + gl + 4);
                xw0[it] = *(const f4*)(v  + rb + gl);
                xw1[it] = *(const f4*)(v  + rb + gl + 4);
            }
        }
        #pragma unroll
        for (int it = 0; it < 5; ++it) {
            const int s = sidx + 16*it;
            const int gl = l0 - HALO + s*8;
            U8 zz; zz.s = (s8v){0,0,0,0,0,0,0,0};
            if (gl >= 0) {
                const f4 z0 = xa0[it]*xw0[it], z1 = xa1[it]*xw1[it];
                zz.u[0] = bf16pk(z0[0], z0[1]);
                zz.u[1] = bf16pk(z0[2], z0[3]);
                zz.u[2] = bf16pk(z1[0], z1[1]);
                zz.u[3] = bf16pk(z1[2], z1[3]);
            }
            *(s8v*)&zb[r][s*8] = zz.s;
        }
    }
    // ---- staging round B: slots 80..143 (16 f4 in flight) ----
    {
        f4 xa0[4], xa1[4], xw0[4], xw1[4];
        #pragma unroll
        for (int it = 0; it < 4; ++it) {
            const int gl = l0 - HALO + (sidx + 16*(it+5))*8;
            xa0[it] = *(const f4*)(x2 + rb + gl);
            xa1[it] = *(const f4*)(x2 + rb + gl + 4);
            xw0[it] = *(const f4*)(v  + rb + gl);
            xw1[it] = *(const f4*)(v  + rb + gl + 4);
        }
        #pragma unroll
        for (int it = 0; it < 4; ++it) {
            const int s = sidx + 16*(it+5);
            const f4 z0 = xa0[it]*xw0[it], z1 = xa1[it]*xw1[it];
            U8 zz;
            zz.u[0] = bf16pk(z0[0], z0[1]);
            zz.u[1] = bf16pk(z0[2], z0[3]);
            zz.u[2] = bf16pk(z1[0], z1[1]);
            zz.u[3] = bf16pk(z1[2], z1[3]);
            *(s8v*)&zb[r][s*8] = zz.s;
        }
    }

    // ---- lane geometry ----
    const int wv = t >> 6, lane = t & 63;
    const int j  = lane & 15, kb = lane >> 4;
    const int qj = j & 3,  cc = j >> 2;
    const int row = wv*4 + cc;
    const int seg = t & 3;
    const size_t chb = ((size_t)(b*DDIM + d0 + row)) * LSEQ + l0;
    const float bd = cb[d0 + row];
    const int g = (d0 >> 2) + wv;

    // ---- A-frags IN REGISTERS (built once per block, R12 recurrence) ----
    const float* __restrict__ hg = h + g*LC;
    const float dd = __expf((float)g * (2.0f/255.0f) * 2.302585092994046f);
    const float t0 = dd * (1.0f/127.0f);
    const int   M0base = j - 8*kb + 16;
    const float rE = __expf(t0);
    const float sU = __expf(-32.0f*t0);
    float pE[8];
    pE[0] = 1.0f;
    #pragma unroll
    for (int e = 1; e < 8; ++e) pE[e] = pE[e-1]*rE;
    float baseU = __expf(-t0*(float)M0base);

    s8v afr[5];
    #pragma unroll
    for (int u = 0; u < 5; ++u) {
        const int M0 = M0base + 32*u;
        float kv[8];
        #pragma unroll
        for (int e = 0; e < 8; ++e) {
            const int m = M0 - e;
            const int mc = m < 0 ? 0 : (m > 127 ? 127 : m);
            const float hv = hg[mc];
            const float w  = ((unsigned)m < 128u) ? baseU*pE[e] : 0.0f;
            kv[e] = hv * w;
        }
        U8 aa;
        aa.u[0] = bf16pk(kv[0], kv[1]);
        aa.u[1] = bf16pk(kv[2], kv[3]);
        aa.u[2] = bf16pk(kv[4], kv[5]);
        aa.u[3] = bf16pk(kv[6], kv[7]);
        afr[u] = aa.s;
        baseU *= sU;
    }
    __syncthreads();

    // ==== two 512-l subtiles: chains + two-half transpose each (R12 machinery) ====
    #pragma unroll
    for (int sub = 0; sub < 2; ++sub) {
        const int SL = sub * 512;

        f4 x1r[8];
        #pragma unroll
        for (int ci = 0; ci < 8; ++ci)
            x1r[ci] = *(const f4*)(x1 + chb + SL + 64*ci + 16*qj + 4*kb);

        f4 ov[8];
        #pragma unroll
        for (int ci = 0; ci < 8; ++ci) {
            const int L = SL + 64*ci + 16*qj;
            f4 acc = {0.f, 0.f, 0.f, 0.f};
            #pragma unroll
            for (int u = 0; u < 5; ++u) {
                int bi = 112 + L + 8*kb - 32*u;   // zb idx incl. halo
                bi = bi < 0 ? 0 : bi;             // clamped reads pair with A == 0
                const s8v bf = *(const s8v*)&zb[row][bi];
                acc = __builtin_amdgcn_mfma_f32_16x16x32_bf16(afr[u], bf, acc, 0, 0, 0);
            }
            const int lo = L + 4*kb;
            const s4v z4 = *(const s4v*)&zb[row][HALO + lo];
            f4 o;
            o[0] = (acc[0] + bf2f(z4[0])*bd) * x1r[ci][0];
            o[1] = (acc[1] + bf2f(z4[1])*bd) * x1r[ci][1];
            o[2] = (acc[2] + bf2f(z4[2])*bd) * x1r[ci][2];
            o[3] = (acc[3] + bf2f(z4[3])*bd) * x1r[ci][3];
            ov[ci] = o;
        }

        #pragma unroll
        for (int hp = 0; hp < 2; ++hp) {
            __syncthreads();                      // ob free (prev half drained)
            #pragma unroll
            for (int ci = 0; ci < 4; ++ci) {
                const int cidx = hp*4 + ci;
                const int J = (4*cidx + qj)*4 + kb - hp*64;   // [0,64)
                ob[row][J ^ (row & 7)] = ov[cidx];
            }
            __syncthreads();
            #pragma unroll
            for (int it = 0; it < 4; ++it) {
                const int ll = (t >> 2) + it*64;  // local l in [0,256)
                const int J = ll >> 2, e = ll & 3;
                f4 o;
                #pragma unroll
                for (int rr2 = 0; rr2 < 4; ++rr2) {
                    const int r2 = seg*4 + rr2;
                    o[rr2] = ((const float*)&ob[r2][J ^ (r2 & 7)])[e];
                }
                __builtin_nontemporal_store(o,
                    (f4*)(out + ((size_t)b*LSEQ + l0 + SL + hp*256 + ll)*DDIM + d0 + seg*4));
            }
        }
    }
}

extern "C" void kernel_launch(void* const* d_in, const int* in_sizes, int n_in,
                              void* d_out, int out_size, void* d_ws, size_t ws_size,
                              hipStream_t stream) {
    const float* x1 = (const float*)d_in[0];
    const float* x2 = (const float*)d_in[1];
    const float* v  = (const float*)d_in[2];
    const float* h  = (const float*)d_in[3];
    const float* cb = (const float*)d_in[4];
    float* outp = (float*)d_out;
    hipLaunchKernelGGL(hyena_mfma_kernel, dim3(1024), dim3(256), 0, stream,
                       x1, x2, v, h, cb, outp);
}